// Round 13
// baseline (401.128 us; speedup 1.0000x reference)
//
#include <hip/hip_runtime.h>

// CrossAttention: prep (LN + W-cvt, one dispatch) -> merged proj GEMM
// (+fused projT epilogue) -> logits GEMM -> softmax -> attnT transpose ->
// merged PV GEMM.
// GEMM = R9's k_gemm256 K-loop verbatim (best measured: 256x256, BK=64,
// 8 waves, 2-buf LDS, 4 phases/tile, counted vmcnt(8), 0-conflict windows,
// ~850-890 TF / 38% MfmaUtil with merged dispatches), with a SECOND operand
// set selected by bz >= NBZ1 (proj img|txt and PV img|txt each run as one
// dispatch; second-pair blocks fill the first pair's ramp-down tail).
// Workspace layout (196 MiB):
//   R1 [0,      64MiB): norm_img|norm_txt  -> later logits/attn
//   R2 [64MiB, 128MiB): proj_img|proj_txt  -> later attnT
//   WB [128MiB,132MiB): W_img|W_txt as bf16
//   R4 [132MiB,196MiB): projT_img|projT_txt (from proj GEMM epilogue)

#define DEV __device__ __forceinline__

typedef short s16x8 __attribute__((ext_vector_type(8)));
typedef float f32x4 __attribute__((ext_vector_type(4)));

DEV unsigned short f2bf(float f){            // fp32 -> bf16, round-nearest-even
  unsigned u = __float_as_uint(f);
  u = (u + 0x7fffu + ((u >> 16) & 1u)) >> 16;
  return (unsigned short)u;
}
DEV float bf2f(unsigned short s){ return __uint_as_float(((unsigned)s) << 16); }

DEV void ldsload16(const void* g, void* l){
  __builtin_amdgcn_global_load_lds((const __attribute__((address_space(1))) void*)g,
                                   (__attribute__((address_space(3))) void*)l, 16, 0, 0);
}

// ---- prep: LayerNorm (both tensors) + weight fp32->bf16 cvt, one dispatch --
// blocks [0, 32768): LN rows (img then txt); blocks [32768, 34816): cvt.
__global__ __launch_bounds__(256) void k_prep(const float* __restrict__ xa,
                                              const float* __restrict__ xb,
                                              const float* __restrict__ w,
                                              const float* __restrict__ b,
                                              unsigned short* __restrict__ ya,
                                              unsigned short* __restrict__ yb,
                                              const float* __restrict__ wa,
                                              const float* __restrict__ wbm,
                                              unsigned short* __restrict__ da,
                                              unsigned short* __restrict__ db){
  int blk = blockIdx.x, tid = threadIdx.x;
  if (blk >= 32768){                          // weight conversion tail
    int i = (blk - 32768) * 256 + tid;        // 524288 float4 chunks total
    const float* s; unsigned short* d; int j;
    if (i < 262144){ s = wa; d = da; j = i; }
    else           { s = wbm; d = db; j = i - 262144; }
    float4 v = ((const float4*)s)[j];
    ushort4 o;
    o.x = f2bf(v.x); o.y = f2bf(v.y); o.z = f2bf(v.z); o.w = f2bf(v.w);
    ((ushort4*)d)[j] = o;
    return;
  }
  int rb = blk;
  const float* x; unsigned short* y;
  if (rb < 16384){ x = xa; y = ya; } else { x = xb; y = yb; rb -= 16384; }
  float4 v = ((const float4*)(x + (size_t)rb * 1024))[tid];
  float s  = v.x + v.y + v.z + v.w;
  float s2 = v.x*v.x + v.y*v.y + v.z*v.z + v.w*v.w;
  #pragma unroll
  for (int o = 32; o > 0; o >>= 1){ s += __shfl_xor(s, o, 64); s2 += __shfl_xor(s2, o, 64); }
  __shared__ float sh[8];
  int wv = tid >> 6, ln = tid & 63;
  if (!ln){ sh[wv] = s; sh[4 + wv] = s2; }
  __syncthreads();
  s  = sh[0] + sh[1] + sh[2] + sh[3];
  s2 = sh[4] + sh[5] + sh[6] + sh[7];
  float mean = s * (1.f/1024.f);
  float var  = s2 * (1.f/1024.f) - mean * mean;
  float rstd = rsqrtf(var + 1e-5f);
  float4 w4 = ((const float4*)w)[tid];
  float4 b4 = ((const float4*)b)[tid];
  ushort4 o;
  o.x = f2bf((v.x-mean)*rstd*w4.x + b4.x);
  o.y = f2bf((v.y-mean)*rstd*w4.y + b4.y);
  o.z = f2bf((v.z-mean)*rstd*w4.z + b4.z);
  o.w = f2bf((v.w-mean)*rstd*w4.w + b4.w);
  ((ushort4*)(y + (size_t)rb * 1024))[tid] = o;
}

// ---------------- bf16 B^T GEMM, 256x256, counted-vmcnt 4-phase ------------
// C[m,n] = scale * sum_k A[m,k]*Bt[n,k] + bias[n].  Requires NT = K/64 >= 3.
// Two operand sets: blocks with bz >= NBZ1 use set 2 (bz rebased).
// WRITE_T: also emit C^T (per-batch [1024][2048], M = 8x2048) via dead LDS.
#define STG(MAT, BASE, LD, T, H) do{                                              \
  ldsload16((BASE) + (size_t)(wave*16 + sfr) * (LD) + (T)*64 + (H)*32 + sq*8,     \
            &MAT[(T)&1][H][wave][0]);                                             \
  ldsload16((BASE) + (size_t)(wave*16 + 128 + sfr) * (LD) + (T)*64 + (H)*32 + sq*8,\
            &MAT[(T)&1][H][wave + 8][0]);                                         \
}while(0)

template<int OUT_BF16, int WRITE_T>
__global__ __launch_bounds__(512, 2) void k_gemm256(const unsigned short* __restrict__ A,
                                                    const unsigned short* __restrict__ Bt,
                                                    void* __restrict__ C,
                                                    unsigned short* __restrict__ ct,
                                                    const float* __restrict__ bias,
                                                    const unsigned short* __restrict__ A2,
                                                    const unsigned short* __restrict__ Bt2,
                                                    void* __restrict__ C2,
                                                    unsigned short* __restrict__ ct2,
                                                    const float* __restrict__ bias2,
                                                    float scale,
                                                    int K, int lda, int ldb, int ldc,
                                                    long sA, long sB, long sC,
                                                    int NBX, int NBY, int NBZ1){
  __shared__ __align__(16) unsigned short SH[65536];        // 128 KiB
  typedef unsigned short (*Buf)[2][16][512];                // [buf][kk][win][512]
  Buf As = (Buf)SH;
  Buf Bs = (Buf)(SH + 32768);
  int nwg = gridDim.x;                       // always a multiple of 8 here
  int bid = blockIdx.x;
  int swz = (bid & 7) * (nwg >> 3) + (bid >> 3);   // bijective XCD swizzle (T1)
  int bx = swz % NBX; int rem = swz / NBX;
  int by = rem % NBY; int bz = rem / NBY;

  const unsigned short* Ap = A; const unsigned short* Bp = Bt;
  void* Cp = C; unsigned short* ctp = ct; const float* bp = bias;
  if (bz >= NBZ1){ bz -= NBZ1; Ap = A2; Bp = Bt2; Cp = C2; ctp = ct2; bp = bias2; }

  int tid = threadIdx.x, lane = tid & 63, wave = tid >> 6;
  int wm = wave >> 2, wn = wave & 3;         // 2 x 4 wave grid
  int q = lane >> 4, fr = lane & 15;
  const unsigned short* Ab = Ap + (size_t)bz * sA + (size_t)by * 256 * lda;
  const unsigned short* Bb = Bp + (size_t)bz * sB + (size_t)bx * 256 * ldb;
  // staging statics: lane writes window chunk `lane`; inverse of placement map
  int v   = (lane & 7) ^ ((lane >> 3) & 7);
  int sfr = 2 * (lane >> 3) + (v >> 2);      // source row within window (0..15)
  int sq  = v & 3;                           // source k-chunk (0..3)
  // read statics: placement of (fr, q) within a window, in shorts
  int roff = ((fr >> 1) << 6) + (((q + ((fr & 1) << 2)) ^ ((fr >> 1) & 7)) << 3);
  int NT = K >> 6;

  f32x4 acc[8][4];
  #pragma unroll
  for (int m = 0; m < 8; ++m)
    #pragma unroll
    for (int n = 0; n < 4; ++n) acc[m][n] = f32x4{0.f, 0.f, 0.f, 0.f};

  // prologue: (0,k0),(0,k1),(1,k0); force (0,k0) A+B, leave 8 in flight
  STG(As, Ab, lda, 0, 0); STG(Bs, Bb, ldb, 0, 0);
  STG(As, Ab, lda, 0, 1); STG(Bs, Bb, ldb, 0, 1);
  STG(As, Ab, lda, 1, 0); STG(Bs, Bb, ldb, 1, 0);
  asm volatile("s_waitcnt vmcnt(8)");
  __builtin_amdgcn_s_barrier();

  for (int t = 0; t < NT; ++t){
    const int buf = t & 1;
    s16x8 bfr[4];
    #pragma unroll
    for (int ph = 0; ph < 4; ++ph){
      const int kk = ph >> 1;
      const unsigned short* Ah = &As[buf][kk][0][0];
      const unsigned short* Bh = &Bs[buf][kk][0][0];
      s16x8 af[4];
      if ((ph & 1) == 0){                    // new k-half: B frags + A m0-3
        #pragma unroll
        for (int n = 0; n < 4; ++n)  bfr[n] = *(const s16x8*)&Bh[(wn*4 + n)*512 + roff];
        #pragma unroll
        for (int mi = 0; mi < 4; ++mi) af[mi] = *(const s16x8*)&Ah[(wm*8 + mi)*512 + roff];
      } else {                               // A m4-7
        #pragma unroll
        for (int mi = 0; mi < 4; ++mi) af[mi] = *(const s16x8*)&Ah[(wm*8 + 4 + mi)*512 + roff];
      }
      if (ph == 0){ if (t + 1 < NT) STG(As, Ab, lda, t + 1, 1); }
      if (ph == 1){ if (t + 1 < NT) STG(Bs, Bb, ldb, t + 1, 1); }
      if (ph == 2){ if (t + 2 < NT) STG(As, Ab, lda, t + 2, 0); }
      if (ph == 3){ if (t + 2 < NT) STG(Bs, Bb, ldb, t + 2, 0); }
      __builtin_amdgcn_s_barrier();
      asm volatile("s_waitcnt lgkmcnt(0)");
      __builtin_amdgcn_sched_barrier(0);     // rule 18: MFMA must not hoist above
      __builtin_amdgcn_s_setprio(1);
      #pragma unroll
      for (int mi = 0; mi < 4; ++mi)
        #pragma unroll
        for (int n = 0; n < 4; ++n)
          acc[(ph&1)*4 + mi][n] = __builtin_amdgcn_mfma_f32_16x16x32_bf16(
              af[mi], bfr[n], acc[(ph&1)*4 + mi][n], 0, 0, 0);
      __builtin_amdgcn_s_setprio(0);
      __builtin_amdgcn_sched_barrier(0);     // keep the wait after the MFMAs
      if (ph & 1){                           // counted fence: retires exactly one
        if (t + 2 < NT) asm volatile("s_waitcnt vmcnt(8)");   // half-tile pair
        else            asm volatile("s_waitcnt vmcnt(0)");   // tail drain
      }
      __builtin_amdgcn_s_barrier();
    }
  }
  // ---- epilogue: row-major C write ----
  size_t cb = (size_t)bz * sC;
  int row0 = by*256 + wm*128 + q*4;
  int col0 = bx*256 + wn*64 + fr;
  #pragma unroll
  for (int m = 0; m < 8; ++m){
    #pragma unroll
    for (int n = 0; n < 4; ++n){
      int col = col0 + n*16;
      float bv = bp ? bp[col] : 0.f;
      #pragma unroll
      for (int j = 0; j < 4; ++j){
        int row = row0 + m*16 + j;
        float vv = acc[m][n][j] * scale + bv;
        if (OUT_BF16) ((unsigned short*)Cp)[cb + (size_t)row*ldc + col] = f2bf(vv);
        else          ((float*)Cp)[cb + (size_t)row*ldc + col] = vv;
      }
    }
  }
  // ---- WRITE_T: transposed write through the (now dead) LDS ----
  if (WRITE_T){
    unsigned short* LT = SH;                 // 256x256 bf16, chunk-swizzled
    __syncthreads();                         // all K-loop LDS use done
    #pragma unroll
    for (int m = 0; m < 8; ++m){
      #pragma unroll
      for (int n = 0; n < 4; ++n){
        int tr = wn*64 + n*16 + fr;          // C column (CT row)
        int tc = wm*128 + m*16 + q*4;        // C row within tile (CT col)
        float bv = bp ? bp[bx*256 + tr] : 0.f;
        ushort4 pk;
        pk.x = f2bf(acc[m][n][0] * scale + bv);
        pk.y = f2bf(acc[m][n][1] * scale + bv);
        pk.z = f2bf(acc[m][n][2] * scale + bv);
        pk.w = f2bf(acc[m][n][3] * scale + bv);
        int idx = tr*256 + (((tc >> 3) ^ (tr & 7)) << 3) + (tc & 7);
        *(ushort4*)&LT[idx] = pk;            // b64, 2-way = free
      }
    }
    __syncthreads();
    // read back 2 rows per instruction (2-way = free), coalesced 16B stores
    int bb = by >> 3;                        // batch (M = 8 x 2048)
    int r2b = (by & 7) * 256;                // row-within-batch base
    unsigned short* ctb = ctp + (size_t)bb * 2097152 + r2b;
    #pragma unroll
    for (int p = 0; p < 16; ++p){
      int rr = p*16 + wave*2 + (lane >> 5);  // CT row within tile (0..255)
      int ci = lane & 31;                    // logical 8-elem chunk (0..31)
      s16x8 rd = *(const s16x8*)&LT[rr*256 + ((ci ^ (rr & 7)) << 3)];
      *(s16x8*)&ctb[(size_t)(bx*256 + rr) * 2048 + ci*8] = rd;
    }
  }
}

// ---------------- bf16 transpose, 64x64 tiles, swizzled LDS ----------------
__global__ __launch_bounds__(256) void k_transpose(const unsigned short* __restrict__ src,
                                                   unsigned short* __restrict__ dst,
                                                   int R, int C, long sS, long sD){
  __shared__ __align__(16) unsigned short tile[64 * 64];
  int tid = threadIdx.x;
  const unsigned short* sb = src + (size_t)blockIdx.z * sS;
  unsigned short* db = dst + (size_t)blockIdx.z * sD;
  int r0 = blockIdx.y * 64, c0 = blockIdx.x * 64;
  #pragma unroll
  for (int i = 0; i < 2; ++i){
    int ci = i * 256 + tid;
    int row = ci >> 3, cch = ci & 7;
    int pos = cch ^ (row & 7) ^ (row >> 3);
    uint4 v = *(const uint4*)&sb[(size_t)(r0 + row) * C + c0 + cch * 8];
    *(uint4*)&tile[row * 64 + pos * 8] = v;
  }
  __syncthreads();
  int ocp = tid >> 3, og = tid & 7;
  int oc = ocp * 2;
  union { uint4 v; unsigned short us[8]; } o0, o1;
  #pragma unroll
  for (int k = 0; k < 8; ++k){
    int r = og * 8 + k;
    int pos = (oc >> 3) ^ (r & 7) ^ (r >> 3);
    unsigned pr = *(const unsigned*)&tile[r * 64 + pos * 8 + (oc & 7)];
    o0.us[k] = (unsigned short)(pr & 0xffffu);
    o1.us[k] = (unsigned short)(pr >> 16);
  }
  *(uint4*)&db[(size_t)(c0 + oc    ) * R + r0 + og * 8] = o0.v;
  *(uint4*)&db[(size_t)(c0 + oc + 1) * R + r0 + og * 8] = o1.v;
}

// ---------------- row softmax over 2048, bf16 in-place ----------------
__global__ __launch_bounds__(256) void k_softmax(unsigned short* __restrict__ a){
  size_t row = blockIdx.x;
  unsigned short* p = a + row * 2048;
  int tid = threadIdx.x;
  union { uint4 v; unsigned short us[8]; } in, out;
  in.v = *(const uint4*)&p[tid * 8];
  float x[8];
  #pragma unroll
  for (int j = 0; j < 8; ++j) x[j] = bf2f(in.us[j]);
  float mx = x[0];
  #pragma unroll
  for (int j = 1; j < 8; ++j) mx = fmaxf(mx, x[j]);
  #pragma unroll
  for (int o = 32; o > 0; o >>= 1) mx = fmaxf(mx, __shfl_xor(mx, o, 64));
  __shared__ float sh[8];
  int wv = tid >> 6, ln = tid & 63;
  if (!ln) sh[wv] = mx;
  __syncthreads();
  mx = fmaxf(fmaxf(sh[0], sh[1]), fmaxf(sh[2], sh[3]));
  float sm = 0.f, e[8];
  #pragma unroll
  for (int j = 0; j < 8; ++j){ e[j] = __expf(x[j] - mx); sm += e[j]; }
  #pragma unroll
  for (int o = 32; o > 0; o >>= 1) sm += __shfl_xor(sm, o, 64);
  if (!ln) sh[4 + wv] = sm;
  __syncthreads();
  sm = sh[4] + sh[5] + sh[6] + sh[7];
  float inv = 1.f / sm;
  #pragma unroll
  for (int j = 0; j < 8; ++j) out.us[j] = f2bf(e[j] * inv);
  *(uint4*)&p[tid * 8] = out.v;
}

extern "C" void kernel_launch(void* const* d_in, const int* in_sizes, int n_in,
                              void* d_out, int out_size, void* d_ws, size_t ws_size,
                              hipStream_t stream) {
  const float* img  = (const float*)d_in[0];   // [8,2048,1024]
  const float* txt  = (const float*)d_in[1];   // [8,2048,1024]
  const float* lnw  = (const float*)d_in[2];   // [1024]
  const float* lnb  = (const float*)d_in[3];   // [1024]
  const float* Wimg = (const float*)d_in[4];   // [1024,1024]
  const float* bimg = (const float*)d_in[5];   // [1024]
  const float* Wtxt = (const float*)d_in[6];   // [1024,1024]
  const float* btxt = (const float*)d_in[7];   // [1024]
  float* out = (float*)d_out;                  // image_out | text_out

  char* ws = (char*)d_ws;
  unsigned short* R1 = (unsigned short*)ws;                   // norms -> logits/attn
  unsigned short* R2 = (unsigned short*)(ws + 67108864);      // proj -> attnT
  unsigned short* WB = (unsigned short*)(ws + 134217728);     // weights bf16
  unsigned short* R4 = (unsigned short*)(ws + 138412032);     // projT img|txt

  const long PB = 2097152;   // proj per-batch elems (2048*1024)
  const long AB = 4194304;   // attn per-batch elems (2048*2048)

  // prep: LN (both tensors) + W cvt, one dispatch
  k_prep<<<34816, 256, 0, stream>>>(img, txt, lnw, lnb, R1, R1 + 16777216,
                                    Wimg, Wtxt, WB, WB + 1048576);
  // Projections (merged img+txt, one dispatch): proj in R2, projT in R4
  k_gemm256<1,1><<<512, 512, 0, stream>>>(
      R1,            WB,           R2,            R4,            bimg,
      R1 + 16777216, WB + 1048576, R2 + 16777216, R4 + 16777216, btxt,
      1.f, 1024, 1024, 1024, 1024, 0, 0, 0, 4, 64, 1);
  // logits[b] = proj_img[b] @ proj_txt[b]^T / 32  -> bf16 in R1 (norms dead)
  k_gemm256<1,0><<<512, 512, 0, stream>>>(
      R2, R2 + 16777216, R1, nullptr, nullptr,
      R2, R2 + 16777216, R1, nullptr, nullptr,
      0.03125f, 1024, 1024, 1024, 2048, PB, PB, AB, 8, 8, 8);
  // softmax rows, in place (R1)
  k_softmax<<<16384, 256, 0, stream>>>(R1);
  // attnT into R2 (proj dead)
  dim3 gat(32, 32, 8);
  k_transpose<<<gat, 256, 0, stream>>>(R1, R2, 2048, 2048, AB, AB);
  // PV (merged img+txt, one dispatch):
  //   bz<8:  image_out[b] = attn[b] @ projT_txt[b]^T
  //   bz>=8: text_out[b]  = attnT[b] @ projT_img[b]^T
  k_gemm256<0,0><<<512, 512, 0, stream>>>(
      R1, R4 + 16777216, out,            nullptr, nullptr,
      R2, R4,            out + 16777216, nullptr, nullptr,
      1.f, 2048, 2048, 2048, 1024, AB, PB, PB, 4, 8, 8);
}

// Round 14
// 398.399 us; speedup vs baseline: 1.0068x; 1.0068x over previous
//
#include <hip/hip_runtime.h>

// CrossAttention: LN -> merged proj GEMM (+fused projT epilogue) -> logits
// GEMM -> softmax -> attnT transpose -> merged PV GEMM.
// GEMM = R9's k_gemm256 K-loop verbatim (best measured: 256x256, BK=64,
// 8 waves, 2-buf LDS, 4 phases/tile, counted vmcnt(8), 0-conflict windows,
// 838 TF / 34% MfmaUtil), extended with a SECOND operand set selected by
// bz >= NBZ1 so independent GEMM pairs (proj img|txt, PV img|txt) run as
// ONE dispatch each -- second-pair blocks fill CUs freed by the first's
// ramp-down tail, hiding tails + 2 launch gaps.
// Workspace layout (196 MiB):
//   R1 [0,      64MiB): norm_img|norm_txt  -> later logits/attn
//   R2 [64MiB, 128MiB): proj_img|proj_txt  -> later attnT
//   WB [128MiB,132MiB): W_img|W_txt as bf16
//   R4 [132MiB,196MiB): projT_img|projT_txt (from proj GEMM epilogue)

#define DEV __device__ __forceinline__

typedef short s16x8 __attribute__((ext_vector_type(8)));
typedef float f32x4 __attribute__((ext_vector_type(4)));

DEV unsigned short f2bf(float f){            // fp32 -> bf16, round-nearest-even
  unsigned u = __float_as_uint(f);
  u = (u + 0x7fffu + ((u >> 16) & 1u)) >> 16;
  return (unsigned short)u;
}
DEV float bf2f(unsigned short s){ return __uint_as_float(((unsigned)s) << 16); }

DEV void ldsload16(const void* g, void* l){
  __builtin_amdgcn_global_load_lds((const __attribute__((address_space(1))) void*)g,
                                   (__attribute__((address_space(3))) void*)l, 16, 0, 0);
}

// ---------------- fp32 -> bf16 convert (both weight matrices) --------------
__global__ __launch_bounds__(256) void k_cvt2(const float* __restrict__ sa,
                                              const float* __restrict__ sb,
                                              unsigned short* __restrict__ da,
                                              unsigned short* __restrict__ db, int n4){
  int i = blockIdx.x * 256 + threadIdx.x;
  const float* s; unsigned short* d; int j;
  if (i < n4){ s = sa; d = da; j = i; }
  else       { s = sb; d = db; j = i - n4; if (j >= n4) return; }
  float4 v = ((const float4*)s)[j];
  ushort4 o;
  o.x = f2bf(v.x); o.y = f2bf(v.y); o.z = f2bf(v.z); o.w = f2bf(v.w);
  ((ushort4*)d)[j] = o;
}

// ------------- LayerNorm (D=1024) fp32 -> bf16, both tensors ---------------
__global__ __launch_bounds__(256) void k_ln2(const float* __restrict__ xa,
                                             const float* __restrict__ xb,
                                             const float* __restrict__ w,
                                             const float* __restrict__ b,
                                             unsigned short* __restrict__ ya,
                                             unsigned short* __restrict__ yb){
  int rb = blockIdx.x, tid = threadIdx.x;
  const float* x; unsigned short* y;
  if (rb < 16384){ x = xa; y = ya; } else { x = xb; y = yb; rb -= 16384; }
  float4 v = ((const float4*)(x + (size_t)rb * 1024))[tid];
  float s  = v.x + v.y + v.z + v.w;
  float s2 = v.x*v.x + v.y*v.y + v.z*v.z + v.w*v.w;
  #pragma unroll
  for (int o = 32; o > 0; o >>= 1){ s += __shfl_xor(s, o, 64); s2 += __shfl_xor(s2, o, 64); }
  __shared__ float sh[8];
  int wv = tid >> 6, ln = tid & 63;
  if (!ln){ sh[wv] = s; sh[4 + wv] = s2; }
  __syncthreads();
  s  = sh[0] + sh[1] + sh[2] + sh[3];
  s2 = sh[4] + sh[5] + sh[6] + sh[7];
  float mean = s * (1.f/1024.f);
  float var  = s2 * (1.f/1024.f) - mean * mean;
  float rstd = rsqrtf(var + 1e-5f);
  float4 w4 = ((const float4*)w)[tid];
  float4 b4 = ((const float4*)b)[tid];
  ushort4 o;
  o.x = f2bf((v.x-mean)*rstd*w4.x + b4.x);
  o.y = f2bf((v.y-mean)*rstd*w4.y + b4.y);
  o.z = f2bf((v.z-mean)*rstd*w4.z + b4.z);
  o.w = f2bf((v.w-mean)*rstd*w4.w + b4.w);
  ((ushort4*)(y + (size_t)rb * 1024))[tid] = o;
}

// ---------------- bf16 B^T GEMM, 256x256, counted-vmcnt 4-phase ------------
// C[m,n] = scale * sum_k A[m,k]*Bt[n,k] + bias[n].  Requires NT = K/64 >= 3.
// Two operand sets: blocks with bz >= NBZ1 use set 2 (bz rebased). Same K,
// lda/ldb/ldc/strides for both sets. WRITE_T: also emit C^T via dead LDS.
#define STG(MAT, BASE, LD, T, H) do{                                              \
  ldsload16((BASE) + (size_t)(wave*16 + sfr) * (LD) + (T)*64 + (H)*32 + sq*8,     \
            &MAT[(T)&1][H][wave][0]);                                             \
  ldsload16((BASE) + (size_t)(wave*16 + 128 + sfr) * (LD) + (T)*64 + (H)*32 + sq*8,\
            &MAT[(T)&1][H][wave + 8][0]);                                         \
}while(0)

template<int OUT_BF16, int WRITE_T>
__global__ __launch_bounds__(512, 2) void k_gemm256(const unsigned short* __restrict__ A,
                                                    const unsigned short* __restrict__ Bt,
                                                    void* __restrict__ C,
                                                    unsigned short* __restrict__ ct,
                                                    const float* __restrict__ bias,
                                                    const unsigned short* __restrict__ A2,
                                                    const unsigned short* __restrict__ Bt2,
                                                    void* __restrict__ C2,
                                                    unsigned short* __restrict__ ct2,
                                                    const float* __restrict__ bias2,
                                                    float scale,
                                                    int K, int lda, int ldb, int ldc,
                                                    long sA, long sB, long sC,
                                                    int NBX, int NBY, int NBZ1){
  __shared__ __align__(16) unsigned short SH[65536];        // 128 KiB
  typedef unsigned short (*Buf)[2][16][512];                // [buf][kk][win][512]
  Buf As = (Buf)SH;
  Buf Bs = (Buf)(SH + 32768);
  int nwg = gridDim.x;                       // always a multiple of 8 here
  int bid = blockIdx.x;
  int swz = (bid & 7) * (nwg >> 3) + (bid >> 3);   // bijective XCD swizzle (T1)
  int bx = swz % NBX; int rem = swz / NBX;
  int by = rem % NBY; int bz = rem / NBY;

  const unsigned short* Ap = A; const unsigned short* Bp = Bt;
  void* Cp = C; unsigned short* ctp = ct; const float* bp = bias;
  if (bz >= NBZ1){ bz -= NBZ1; Ap = A2; Bp = Bt2; Cp = C2; ctp = ct2; bp = bias2; }

  int tid = threadIdx.x, lane = tid & 63, wave = tid >> 6;
  int wm = wave >> 2, wn = wave & 3;         // 2 x 4 wave grid
  int q = lane >> 4, fr = lane & 15;
  const unsigned short* Ab = Ap + (size_t)bz * sA + (size_t)by * 256 * lda;
  const unsigned short* Bb = Bp + (size_t)bz * sB + (size_t)bx * 256 * ldb;
  // staging statics: lane writes window chunk `lane`; inverse of placement map
  int v   = (lane & 7) ^ ((lane >> 3) & 7);
  int sfr = 2 * (lane >> 3) + (v >> 2);      // source row within window (0..15)
  int sq  = v & 3;                           // source k-chunk (0..3)
  // read statics: placement of (fr, q) within a window, in shorts
  int roff = ((fr >> 1) << 6) + (((q + ((fr & 1) << 2)) ^ ((fr >> 1) & 7)) << 3);
  int NT = K >> 6;

  f32x4 acc[8][4];
  #pragma unroll
  for (int m = 0; m < 8; ++m)
    #pragma unroll
    for (int n = 0; n < 4; ++n) acc[m][n] = f32x4{0.f, 0.f, 0.f, 0.f};

  // prologue: (0,k0),(0,k1),(1,k0); force (0,k0) A+B, leave 8 in flight
  STG(As, Ab, lda, 0, 0); STG(Bs, Bb, ldb, 0, 0);
  STG(As, Ab, lda, 0, 1); STG(Bs, Bb, ldb, 0, 1);
  STG(As, Ab, lda, 1, 0); STG(Bs, Bb, ldb, 1, 0);
  asm volatile("s_waitcnt vmcnt(8)");
  __builtin_amdgcn_s_barrier();

  for (int t = 0; t < NT; ++t){
    const int buf = t & 1;
    s16x8 bfr[4];
    #pragma unroll
    for (int ph = 0; ph < 4; ++ph){
      const int kk = ph >> 1;
      const unsigned short* Ah = &As[buf][kk][0][0];
      const unsigned short* Bh = &Bs[buf][kk][0][0];
      s16x8 af[4];
      if ((ph & 1) == 0){                    // new k-half: B frags + A m0-3
        #pragma unroll
        for (int n = 0; n < 4; ++n)  bfr[n] = *(const s16x8*)&Bh[(wn*4 + n)*512 + roff];
        #pragma unroll
        for (int mi = 0; mi < 4; ++mi) af[mi] = *(const s16x8*)&Ah[(wm*8 + mi)*512 + roff];
      } else {                               // A m4-7
        #pragma unroll
        for (int mi = 0; mi < 4; ++mi) af[mi] = *(const s16x8*)&Ah[(wm*8 + 4 + mi)*512 + roff];
      }
      if (ph == 0){ if (t + 1 < NT) STG(As, Ab, lda, t + 1, 1); }
      if (ph == 1){ if (t + 1 < NT) STG(Bs, Bb, ldb, t + 1, 1); }
      if (ph == 2){ if (t + 2 < NT) STG(As, Ab, lda, t + 2, 0); }
      if (ph == 3){ if (t + 2 < NT) STG(Bs, Bb, ldb, t + 2, 0); }
      __builtin_amdgcn_s_barrier();
      asm volatile("s_waitcnt lgkmcnt(0)");
      __builtin_amdgcn_sched_barrier(0);     // rule 18: MFMA must not hoist above
      __builtin_amdgcn_s_setprio(1);
      #pragma unroll
      for (int mi = 0; mi < 4; ++mi)
        #pragma unroll
        for (int n = 0; n < 4; ++n)
          acc[(ph&1)*4 + mi][n] = __builtin_amdgcn_mfma_f32_16x16x32_bf16(
              af[mi], bfr[n], acc[(ph&1)*4 + mi][n], 0, 0, 0);
      __builtin_amdgcn_s_setprio(0);
      __builtin_amdgcn_sched_barrier(0);     // keep the wait after the MFMAs
      if (ph & 1){                           // counted fence: retires exactly one
        if (t + 2 < NT) asm volatile("s_waitcnt vmcnt(8)");   // half-tile pair
        else            asm volatile("s_waitcnt vmcnt(0)");   // tail drain
      }
      __builtin_amdgcn_s_barrier();
    }
  }
  // ---- epilogue: row-major C write ----
  size_t cb = (size_t)bz * sC;
  int row0 = by*256 + wm*128 + q*4;
  int col0 = bx*256 + wn*64 + fr;
  #pragma unroll
  for (int m = 0; m < 8; ++m){
    #pragma unroll
    for (int n = 0; n < 4; ++n){
      int col = col0 + n*16;
      float bv = bp ? bp[col] : 0.f;
      #pragma unroll
      for (int j = 0; j < 4; ++j){
        int row = row0 + m*16 + j;
        float vv = acc[m][n][j] * scale + bv;
        if (OUT_BF16) ((unsigned short*)Cp)[cb + (size_t)row*ldc + col] = f2bf(vv);
        else          ((float*)Cp)[cb + (size_t)row*ldc + col] = vv;
      }
    }
  }
  // ---- WRITE_T: transposed write through the (now dead) LDS ----
  if (WRITE_T){
    unsigned short* LT = SH;                 // 256x256 bf16, chunk-swizzled
    __syncthreads();                         // all K-loop LDS use done
    #pragma unroll
    for (int m = 0; m < 8; ++m){
      #pragma unroll
      for (int n = 0; n < 4; ++n){
        int tr = wn*64 + n*16 + fr;          // C column (CT row)
        int tc = wm*128 + m*16 + q*4;        // C row within tile (CT col)
        float bv = bp ? bp[bx*256 + tr] : 0.f;
        ushort4 pk;
        pk.x = f2bf(acc[m][n][0] * scale + bv);
        pk.y = f2bf(acc[m][n][1] * scale + bv);
        pk.z = f2bf(acc[m][n][2] * scale + bv);
        pk.w = f2bf(acc[m][n][3] * scale + bv);
        int idx = tr*256 + (((tc >> 3) ^ (tr & 7)) << 3) + (tc & 7);
        *(ushort4*)&LT[idx] = pk;            // b64, 2-way = free
      }
    }
    __syncthreads();
    // read back 2 rows per instruction (2-way = free), coalesced 16B stores
    int bb = by >> 3;                        // batch (M = 8 x 2048)
    int r2b = (by & 7) * 256;                // row-within-batch base
    unsigned short* ctb = ctp + (size_t)bb * 2097152 + r2b;
    #pragma unroll
    for (int p = 0; p < 16; ++p){
      int rr = p*16 + wave*2 + (lane >> 5);  // CT row within tile (0..255)
      int ci = lane & 31;                    // logical 8-elem chunk (0..31)
      s16x8 rd = *(const s16x8*)&LT[rr*256 + ((ci ^ (rr & 7)) << 3)];
      *(s16x8*)&ctb[(size_t)(bx*256 + rr) * 2048 + ci*8] = rd;
    }
  }
}

// ---------------- bf16 transpose, 64x64 tiles, swizzled LDS ----------------
__global__ __launch_bounds__(256) void k_transpose(const unsigned short* __restrict__ src,
                                                   unsigned short* __restrict__ dst,
                                                   int R, int C, long sS, long sD){
  __shared__ __align__(16) unsigned short tile[64 * 64];
  int tid = threadIdx.x;
  const unsigned short* sb = src + (size_t)blockIdx.z * sS;
  unsigned short* db = dst + (size_t)blockIdx.z * sD;
  int r0 = blockIdx.y * 64, c0 = blockIdx.x * 64;
  #pragma unroll
  for (int i = 0; i < 2; ++i){
    int ci = i * 256 + tid;
    int row = ci >> 3, cch = ci & 7;
    int pos = cch ^ (row & 7) ^ (row >> 3);
    uint4 v = *(const uint4*)&sb[(size_t)(r0 + row) * C + c0 + cch * 8];
    *(uint4*)&tile[row * 64 + pos * 8] = v;
  }
  __syncthreads();
  int ocp = tid >> 3, og = tid & 7;
  int oc = ocp * 2;
  union { uint4 v; unsigned short us[8]; } o0, o1;
  #pragma unroll
  for (int k = 0; k < 8; ++k){
    int r = og * 8 + k;
    int pos = (oc >> 3) ^ (r & 7) ^ (r >> 3);
    unsigned pr = *(const unsigned*)&tile[r * 64 + pos * 8 + (oc & 7)];
    o0.us[k] = (unsigned short)(pr & 0xffffu);
    o1.us[k] = (unsigned short)(pr >> 16);
  }
  *(uint4*)&db[(size_t)(c0 + oc    ) * R + r0 + og * 8] = o0.v;
  *(uint4*)&db[(size_t)(c0 + oc + 1) * R + r0 + og * 8] = o1.v;
}

// ---------------- row softmax over 2048, bf16 in-place ----------------
__global__ __launch_bounds__(256) void k_softmax(unsigned short* __restrict__ a){
  size_t row = blockIdx.x;
  unsigned short* p = a + row * 2048;
  int tid = threadIdx.x;
  union { uint4 v; unsigned short us[8]; } in, out;
  in.v = *(const uint4*)&p[tid * 8];
  float x[8];
  #pragma unroll
  for (int j = 0; j < 8; ++j) x[j] = bf2f(in.us[j]);
  float mx = x[0];
  #pragma unroll
  for (int j = 1; j < 8; ++j) mx = fmaxf(mx, x[j]);
  #pragma unroll
  for (int o = 32; o > 0; o >>= 1) mx = fmaxf(mx, __shfl_xor(mx, o, 64));
  __shared__ float sh[8];
  int wv = tid >> 6, ln = tid & 63;
  if (!ln) sh[wv] = mx;
  __syncthreads();
  mx = fmaxf(fmaxf(sh[0], sh[1]), fmaxf(sh[2], sh[3]));
  float sm = 0.f, e[8];
  #pragma unroll
  for (int j = 0; j < 8; ++j){ e[j] = __expf(x[j] - mx); sm += e[j]; }
  #pragma unroll
  for (int o = 32; o > 0; o >>= 1) sm += __shfl_xor(sm, o, 64);
  if (!ln) sh[4 + wv] = sm;
  __syncthreads();
  sm = sh[4] + sh[5] + sh[6] + sh[7];
  float inv = 1.f / sm;
  #pragma unroll
  for (int j = 0; j < 8; ++j) out.us[j] = f2bf(e[j] * inv);
  *(uint4*)&p[tid * 8] = out.v;
}

extern "C" void kernel_launch(void* const* d_in, const int* in_sizes, int n_in,
                              void* d_out, int out_size, void* d_ws, size_t ws_size,
                              hipStream_t stream) {
  const float* img  = (const float*)d_in[0];   // [8,2048,1024]
  const float* txt  = (const float*)d_in[1];   // [8,2048,1024]
  const float* lnw  = (const float*)d_in[2];   // [1024]
  const float* lnb  = (const float*)d_in[3];   // [1024]
  const float* Wimg = (const float*)d_in[4];   // [1024,1024]
  const float* bimg = (const float*)d_in[5];   // [1024]
  const float* Wtxt = (const float*)d_in[6];   // [1024,1024]
  const float* btxt = (const float*)d_in[7];   // [1024]
  float* out = (float*)d_out;                  // image_out | text_out

  char* ws = (char*)d_ws;
  unsigned short* R1 = (unsigned short*)ws;                   // norms -> logits/attn
  unsigned short* R2 = (unsigned short*)(ws + 67108864);      // proj -> attnT
  unsigned short* WB = (unsigned short*)(ws + 134217728);     // weights bf16
  unsigned short* R4 = (unsigned short*)(ws + 138412032);     // projT img|txt

  const long PB = 2097152;   // proj per-batch elems (2048*1024)
  const long AB = 4194304;   // attn per-batch elems (2048*2048)

  // W -> bf16 (one dispatch)
  k_cvt2<<<2048, 256, 0, stream>>>(Wimg, Wtxt, WB, WB + 1048576, 262144);
  // LayerNorm -> bf16 norms in R1 (both tensors, one dispatch)
  k_ln2<<<32768, 256, 0, stream>>>(img, txt, lnw, lnb, R1, R1 + 16777216);
  // Projections (merged img+txt, one dispatch): proj in R2, projT in R4
  k_gemm256<1,1><<<512, 512, 0, stream>>>(
      R1,            WB,           R2,            R4,            bimg,
      R1 + 16777216, WB + 1048576, R2 + 16777216, R4 + 16777216, btxt,
      1.f, 1024, 1024, 1024, 1024, 0, 0, 0, 4, 64, 1);
  // logits[b] = proj_img[b] @ proj_txt[b]^T / 32  -> bf16 in R1 (norms dead)
  k_gemm256<1,0><<<512, 512, 0, stream>>>(
      R2, R2 + 16777216, R1, nullptr, nullptr,
      R2, R2 + 16777216, R1, nullptr, nullptr,
      0.03125f, 1024, 1024, 1024, 2048, PB, PB, AB, 8, 8, 8);
  // softmax rows, in place (R1)
  k_softmax<<<16384, 256, 0, stream>>>(R1);
  // attnT into R2 (proj dead)
  dim3 gat(32, 32, 8);
  k_transpose<<<gat, 256, 0, stream>>>(R1, R2, 2048, 2048, AB, AB);
  // PV (merged img+txt, one dispatch):
  //   bz<8:  image_out[b] = attn[b] @ projT_txt[b]^T
  //   bz>=8: text_out[b]  = attnT[b] @ projT_img[b]^T
  k_gemm256<0,0><<<512, 512, 0, stream>>>(
      R1, R4 + 16777216, out,            nullptr, nullptr,
      R2, R4,            out + 16777216, nullptr, nullptr,
      1.f, 2048, 2048, 2048, 1024, AB, PB, PB, 4, 8, 8);
}